// Round 11
// baseline (391.851 us; speedup 1.0000x reference)
//
#include <hip/hip_runtime.h>

// B=8, C=256, Cp=32, N=4096.
// o[b,c,m] = gamma * sum_n h[b,c,n] * softmax_n(f^T g)[n,m] + x[b,c,m]
// R16: attn register-diet for 3 blocks/CU. launch_bounds(512,6) (cap 85);
// h loaded per-ch inside PV (8 regs vs 32-reg ah[2][4] prefetch), bp per-ms
// (4 regs vs 16). Peak ~80 regs < 85 -> no spill (R11's 96>85 was the
// failure). LDS 51.7KB x3 = 155.1 <= 160KB -> 24 waves/CU (was 16).
// Trades intra-wave h-prefetch for +50% TLP. Producer/wconv = R15 exact.

typedef __attribute__((ext_vector_type(8))) short bf16x8;    // 8 bf16
typedef __attribute__((ext_vector_type(4))) float f32x4;
typedef __attribute__((ext_vector_type(4))) unsigned short us4;

#define LOG2E 1.44269504088896f

static __device__ __forceinline__ unsigned short f2bf(float x) {
    union { float f; unsigned u; } v; v.f = x;
    unsigned r = v.u + 0x7FFFu + ((v.u >> 16) & 1u);   // RNE
    return (unsigned short)(r >> 16);
}
static __device__ __forceinline__ float bf2f(unsigned short u) {
    union { unsigned u; float f; } v; v.u = ((unsigned)u) << 16;
    return v.f;
}

// ------------------------------------------------ weight convert (fp32->bf16)
__global__ __launch_bounds__(256) void wconv_kernel(
    const float* __restrict__ Wq, const float* __restrict__ Wk,
    const float* __restrict__ Wv, unsigned short* __restrict__ wq,
    unsigned short* __restrict__ wk, unsigned short* __restrict__ wv)
{
    const int i = blockIdx.x * 256 + threadIdx.x;   // 320 blocks -> 81920
    if (i < 8192)            wq[i] = f2bf(Wq[i] * LOG2E);
    else if (i < 16384)      wk[i - 8192] = f2bf(Wk[i - 8192]);
    else                     wv[i - 16384] = f2bf(Wv[i - 16384]);
}

// --------------------------------------------------- fused f,g,h producer
// R9 version: x LDS stage + 2-pass h (32 acc regs/pass), wave-private h stage.
#define XPITCH 264
#define HSPITCH 72
__global__ __launch_bounds__(256, 2) void producer_kernel(
    const float* __restrict__ x, const unsigned short* __restrict__ wq,
    const unsigned short* __restrict__ wk, const unsigned short* __restrict__ wv,
    unsigned short* __restrict__ f_t, unsigned short* __restrict__ g_t,
    unsigned short* __restrict__ h_bf, float* __restrict__ normg,
    float* __restrict__ pmax)
{
    __shared__ unsigned short xh_s[64 * XPITCH];        // 33.8 KB x-tile [n][c]
    __shared__ unsigned short hst[4 * 32 * HSPITCH];    // 18 KB h stage (wave-private)
    __shared__ unsigned short fg_s[4 * 2 * 512];        // 8 KB

    const int tid  = threadIdx.x;
    const int w    = tid >> 6;
    const int lane = tid & 63;
    const int q    = lane >> 4;
    const int r    = lane & 15;
    const int b    = blockIdx.x & 7;     // XCD pin
    const int nt   = blockIdx.x >> 3;
    const int n0   = nt << 6;
    const size_t bN = (size_t)b << 12;
    const f32x4 zero = {0.f, 0.f, 0.f, 0.f};

    // ---- stage x[b, :, n0..n0+64) as bf16, layout [n][c], pitch XPITCH ----
#pragma unroll
    for (int jj = 0; jj < 4; jj++) {
        const int task = jj * 256 + tid;
        const int n4 = task & 15;
        const int c4 = task >> 4;
        float va[4][4];
#pragma unroll
        for (int i = 0; i < 4; i++) {
            const f32x4 v = __builtin_nontemporal_load(
                (const f32x4*)(x + ((size_t)b << 20)
                               + (size_t)(c4 * 4 + i) * 4096 + n0) + n4);
            va[i][0] = v.x; va[i][1] = v.y; va[i][2] = v.z; va[i][3] = v.w;
        }
#pragma unroll
        for (int i = 0; i < 4; i++) {
            us4 t;
            t.x = f2bf(va[0][i]); t.y = f2bf(va[1][i]);
            t.z = f2bf(va[2][i]); t.w = f2bf(va[3][i]);
            *(us4*)(xh_s + (n4 * 4 + i) * XPITCH + c4 * 4) = t;
        }
    }
    __syncthreads();
    // xh_s is read-only from here on -> no further block barriers needed.

    f32x4 accf[2], accg[2];
    accf[0] = accf[1] = accg[0] = accg[1] = zero;

#pragma unroll
    for (int pass = 0; pass < 2; pass++) {
        f32x4 acch[2][4];
#pragma unroll
        for (int cs = 0; cs < 2; cs++)
#pragma unroll
            for (int ns = 0; ns < 4; ns++) acch[cs][ns] = zero;

        for (int ks = 0; ks < 8; ks++) {
            const int kof = ks * 32 + q * 8;
            const bf16x8 av0 = *(const bf16x8*)(wv + (size_t)(w * 64 + pass * 32 + r) * 256 + kof);
            const bf16x8 av1 = *(const bf16x8*)(wv + (size_t)(w * 64 + pass * 32 + 16 + r) * 256 + kof);
            bf16x8 aq0, aq1, ak0, ak1;
            if (pass == 0) {
                aq0 = *(const bf16x8*)(wq + (size_t)(r) * 256 + kof);
                aq1 = *(const bf16x8*)(wq + (size_t)(16 + r) * 256 + kof);
                ak0 = *(const bf16x8*)(wk + (size_t)(r) * 256 + kof);
                ak1 = *(const bf16x8*)(wk + (size_t)(16 + r) * 256 + kof);
            }
#pragma unroll
            for (int ns = 0; ns < 4; ns++) {
                const bf16x8 bx = *(const bf16x8*)(xh_s + (ns * 16 + r) * XPITCH + kof);
                acch[0][ns] = __builtin_amdgcn_mfma_f32_16x16x32_bf16(av0, bx, acch[0][ns], 0, 0, 0);
                acch[1][ns] = __builtin_amdgcn_mfma_f32_16x16x32_bf16(av1, bx, acch[1][ns], 0, 0, 0);
                if (pass == 0 && ns == w) {
                    accf[0] = __builtin_amdgcn_mfma_f32_16x16x32_bf16(aq0, bx, accf[0], 0, 0, 0);
                    accf[1] = __builtin_amdgcn_mfma_f32_16x16x32_bf16(aq1, bx, accf[1], 0, 0, 0);
                    accg[0] = __builtin_amdgcn_mfma_f32_16x16x32_bf16(ak0, bx, accg[0], 0, 0, 0);
                    accg[1] = __builtin_amdgcn_mfma_f32_16x16x32_bf16(ak1, bx, accg[1], 0, 0, 0);
                }
            }
        }

        // ---- f/g output + norms (pass 0 only; all wave-local) ----
        if (pass == 0) {
            unsigned short* lf = fg_s + w * 1024;
            unsigned short* lg = lf + 512;
#pragma unroll
            for (int ms = 0; ms < 2; ms++)
#pragma unroll
                for (int reg = 0; reg < 4; reg++) {
                    lf[r * 32 + ms * 16 + q * 4 + reg] = f2bf(fmaxf(accf[ms][reg], 0.f));
                    lg[r * 32 + ms * 16 + q * 4 + reg] = f2bf(fmaxf(accg[ms][reg], 0.f));
                }
            const bf16x8 ffrag = *(const bf16x8*)(lf + r * 32 + q * 8);
            const bf16x8 gfrag = *(const bf16x8*)(lg + r * 32 + q * 8);
            *(bf16x8*)(f_t + ((bN + n0 + w * 16 + r) << 5) + q * 8) = ffrag;
            *(bf16x8*)(g_t + ((bN + n0 + w * 16 + r) << 5) + q * 8) = gfrag;

            float nf2 = 0.f, ng2 = 0.f;
#pragma unroll
            for (int i = 0; i < 8; i++) {
                const float fv = bf2f(((unsigned short*)&ffrag)[i]);
                const float gv = bf2f(((unsigned short*)&gfrag)[i]);
                nf2 += fv * fv; ng2 += gv * gv;
            }
            nf2 += __shfl_xor(nf2, 16); nf2 += __shfl_xor(nf2, 32);
            ng2 += __shfl_xor(ng2, 16); ng2 += __shfl_xor(ng2, 32);
            if (q == 0) normg[bN + n0 + w * 16 + r] = sqrtf(ng2);
            float nf = sqrtf(nf2);
#pragma unroll
            for (int off = 1; off < 16; off <<= 1) nf = fmaxf(nf, __shfl_xor(nf, off));
            if (lane == 0) pmax[(b << 8) + nt * 4 + w] = nf;
        }

        // ---- stage h (relu) wave-privately, then store 32 rows of 128B ----
        unsigned short* hs = hst + w * (32 * HSPITCH);
#pragma unroll
        for (int cs = 0; cs < 2; cs++)
#pragma unroll
            for (int ns = 0; ns < 4; ns++)
#pragma unroll
                for (int reg = 0; reg < 4; reg++)
                    hs[(cs * 16 + q * 4 + reg) * HSPITCH + ns * 16 + r] =
                        f2bf(fmaxf(acch[cs][ns][reg], 0.f));
        const size_t hdst = (((size_t)(b * 64 + nt)) << 14)
                          + (size_t)(w * 64 + pass * 32) * 64;
#pragma unroll
        for (int p = 0; p < 4; p++) {
            const int cl = p * 8 + (lane >> 3);
            const int kk = lane & 7;
            *(bf16x8*)(h_bf + hdst + cl * 64 + kk * 8) =
                *(const bf16x8*)(hs + cl * HSPITCH + kk * 8);
        }
    }
}

// ------------------------------------------------------- MFMA attention
// R16: R8 structure (512 thr / 8 waves, c-split 32, 3-slot XOR-swizzled P,
// 1 barrier/iter) but register-dieted for (512,6): h loaded per-ch in PV
// (8 regs), bp per-ms (4 regs). Peak ~80 regs < 85 cap -> 3 blocks/CU.
__global__ __launch_bounds__(512, 6) void attn_kernel(
    const unsigned short* __restrict__ f_t, const unsigned short* __restrict__ g_t,
    const unsigned short* __restrict__ h_bf, const float* __restrict__ x,
    const float* __restrict__ gamma, const float* __restrict__ normg,
    const float* __restrict__ pmax, float* __restrict__ out)
{
    __shared__ unsigned short p_s[3][64 * 128];  // [slot][m][n], XOR-swizzled
    __shared__ float red_l[8][64];
    __shared__ float sLi[64];

    const int tid  = threadIdx.x;
    const int w    = tid >> 6;      // wave 0..7
    const int lane = tid & 63;
    const int q    = lane >> 4;
    const int r    = lane & 15;
    const int b    = blockIdx.x & 7;          // XCD pin
    const int m0   = (blockIdx.x >> 3) << 6;

    const size_t bN = (size_t)b << 12;
    const int c0 = w << 5;                    // 32 channels per wave

    // reduce per-wave f-norm partials (256 floats, L2-hit) -> mnf
    float pv = pmax[(b << 8) + lane];
    pv = fmaxf(pv, pmax[(b << 8) + 64 + lane]);
    pv = fmaxf(pv, pmax[(b << 8) + 128 + lane]);
    pv = fmaxf(pv, pmax[(b << 8) + 192 + lane]);
#pragma unroll
    for (int off = 1; off < 64; off <<= 1) pv = fmaxf(pv, __shfl_xor(pv, off));
    const float mnf = pv;

    bf16x8 bg[4];
    float nMh[4];
#pragma unroll
    for (int ms = 0; ms < 4; ms++) {
        bg[ms] = *(const bf16x8*)(g_t + ((bN + m0 + ms * 16 + r) << 5) + (q << 3));
        nMh[ms] = -(mnf * normg[bN + m0 + ms * 16 + r] * 1.0002f);
    }

    f32x4 acc[2][4];
    const f32x4 zero = {0.f, 0.f, 0.f, 0.f};
#pragma unroll
    for (int cs = 0; cs < 2; cs++)
#pragma unroll
        for (int ms = 0; ms < 4; ms++) acc[cs][ms] = zero;
    float lt[4] = {0.f, 0.f, 0.f, 0.f};

    // swizzle: 16B chunk idx within a 256B row, phys = (idx&8)|((idx^r)&7)
    const int wchunk = (w << 1) + (q >> 1);                         // write: 0..15
    const int wphys  = (wchunk & 8) | ((wchunk ^ r) & 7);
    const int woff   = (wphys << 3) + ((q & 1) << 2);               // u16 units

    auto ldf = [&](int t) {   // f rows n = t*128 + w*16 + r
        return *(const bf16x8*)(f_t + ((bN + (t << 7) + (w << 4) + r) << 5) + (q << 3));
    };
    auto produce = [&](const bf16x8 af, unsigned short* pb) {
#pragma unroll
        for (int ms = 0; ms < 4; ms++) {
            f32x4 ci; ci[0] = ci[1] = ci[2] = ci[3] = nMh[ms];
            const f32x4 sv = __builtin_amdgcn_mfma_f32_16x16x32_bf16(af, bg[ms], ci, 0, 0, 0);
            const float e0 = __builtin_amdgcn_exp2f(sv[0]);
            const float e1 = __builtin_amdgcn_exp2f(sv[1]);
            const float e2 = __builtin_amdgcn_exp2f(sv[2]);
            const float e3 = __builtin_amdgcn_exp2f(sv[3]);
            lt[ms] += (e0 + e1) + (e2 + e3);
            uint2 pk;
            pk.x = __builtin_amdgcn_perm(__float_as_uint(e1), __float_as_uint(e0), 0x07060302u);
            pk.y = __builtin_amdgcn_perm(__float_as_uint(e3), __float_as_uint(e2), 0x07060302u);
            *(uint2*)(pb + ((ms * 16 + r) << 7) + woff) = pk;
        }
    };

    bf16x8 afn = ldf(0);
    produce(afn, p_s[0]);
    afn = ldf(1);

    int sr = 0, sw = 1;
    for (int t = 0; t < 32; t++) {
        __syncthreads();
        if (t < 31) {
            const bf16x8 afc = afn;
            if (t < 30) afn = ldf(t + 2);
            produce(afc, p_s[sw]);
        }
        // PV(t): per-ch h loads (8 regs live), per-ms bp loads (4 regs live)
        const unsigned short* pb = p_s[sr];
#pragma unroll
        for (int ch = 0; ch < 4; ch++) {
            const unsigned short* hb =
                h_bf + (((size_t)(b * 64 + t * 2 + (ch >> 1))) << 14) + ((ch & 1) << 5) + (q << 3);
            const bf16x8 ah0 = *(const bf16x8*)(hb + ((c0 + r) << 6));
            const bf16x8 ah1 = *(const bf16x8*)(hb + ((c0 + 16 + r) << 6));
#pragma unroll
            for (int ms = 0; ms < 4; ms++) {
                const int idx  = (ch << 2) + q;
                const int phys = (idx & 8) | ((idx ^ r) & 7);
                const bf16x8 bp = *(const bf16x8*)(pb + ((ms * 16 + r) << 7) + (phys << 3));
                acc[0][ms] = __builtin_amdgcn_mfma_f32_16x16x32_bf16(ah0, bp, acc[0][ms], 0, 0, 0);
                acc[1][ms] = __builtin_amdgcn_mfma_f32_16x16x32_bf16(ah1, bp, acc[1][ms], 0, 0, 0);
            }
        }
        sr = sw;
        sw = (sw == 2) ? 0 : sw + 1;
    }

    // ---------------- L reduction ------------------------------------------
#pragma unroll
    for (int ms = 0; ms < 4; ms++) {
        lt[ms] += __shfl_xor(lt[ms], 16);
        lt[ms] += __shfl_xor(lt[ms], 32);
    }
    __syncthreads();
    if (q == 0)
#pragma unroll
        for (int ms = 0; ms < 4; ms++) red_l[w][ms * 16 + r] = lt[ms];
    __syncthreads();
    if (tid < 64) {
        float L = 0.f;
#pragma unroll
        for (int ww = 0; ww < 8; ww++) L += red_l[ww][tid];
        sLi[tid] = 1.f / L;
    }
    __syncthreads();

    // ---------------- epilogue: (gamma/L) * O + x (nontemporal) ------------
    const float gm = gamma[0];
#pragma unroll
    for (int cs = 0; cs < 2; cs++) {
#pragma unroll
        for (int ms = 0; ms < 4; ms++) {
            const float gl = gm * sLi[ms * 16 + r];
#pragma unroll
            for (int reg = 0; reg < 4; reg++) {
                const int c = c0 + cs * 16 + q * 4 + reg;
                const size_t a = (((size_t)b * 256 + c) << 12) + m0 + ms * 16 + r;
                const float xv = __builtin_nontemporal_load(x + a);
                __builtin_nontemporal_store(gl * acc[cs][ms][reg] + xv, out + a);
            }
        }
    }
}

// ------------------------------------------------------------------- launch
extern "C" void kernel_launch(void* const* d_in, const int* in_sizes, int n_in,
                              void* d_out, int out_size, void* d_ws, size_t ws_size,
                              hipStream_t stream) {
    const float* x     = (const float*)d_in[0];
    const float* Wq    = (const float*)d_in[1];
    const float* Wk    = (const float*)d_in[2];
    const float* Wv    = (const float*)d_in[3];
    const float* gamma = (const float*)d_in[4];
    float* out = (float*)d_out;

    char* ws = (char*)d_ws;
    unsigned short* f_t  = (unsigned short*)ws;                        // 2 MB
    unsigned short* g_t  = (unsigned short*)(ws + (2u << 20));         // 2 MB
    unsigned short* h_bf = (unsigned short*)(ws + (4u << 20));         // 16 MB
    float*          ng   = (float*)(ws + (20u << 20));                 // 128 KB
    float*          pmx  = (float*)(ws + (20u << 20) + (1u << 17));    // 8 KB
    unsigned short* wq   = (unsigned short*)(ws + (21u << 20));        // 16 KB
    unsigned short* wk   = wq + 8192;                                  // 16 KB
    unsigned short* wv   = wk + 8192;                                  // 128 KB

    wconv_kernel<<<dim3(320), 256, 0, stream>>>(Wq, Wk, Wv, wq, wk, wv);
    producer_kernel<<<dim3(512), 256, 0, stream>>>(x, wq, wk, wv, f_t, g_t, h_bf, ng, pmx);
    attn_kernel<<<dim3(512), 512, 0, stream>>>(f_t, g_t, h_bf, x, gamma, ng, pmx, out);
}

// Round 12
// 248.101 us; speedup vs baseline: 1.5794x; 1.5794x over previous
//
#include <hip/hip_runtime.h>

// B=8, C=256, Cp=32, N=4096.
// o[b,c,m] = gamma * sum_n h[b,c,n] * softmax_n(f^T g)[n,m] + x[b,c,m]
// R17 = R15 exact revert (session best, 249.4us). R16's (512,6) register
// diet spilled (VGPR 40 + scratch, FETCH 552MB, attn 302us) -- second and
// final proof that the ~96-reg attn body cannot fit the 85-reg cap needed
// for 3 blocks/CU; (512,5) gives no third block (8-wave granularity).
// attn = R8 structure (150.2-153.6us x7, 8 variants all worse).
// producer = R9 2-pass. Practical structure floor.

typedef __attribute__((ext_vector_type(8))) short bf16x8;    // 8 bf16
typedef __attribute__((ext_vector_type(4))) float f32x4;
typedef __attribute__((ext_vector_type(4))) unsigned short us4;

#define LOG2E 1.44269504088896f

static __device__ __forceinline__ unsigned short f2bf(float x) {
    union { float f; unsigned u; } v; v.f = x;
    unsigned r = v.u + 0x7FFFu + ((v.u >> 16) & 1u);   // RNE
    return (unsigned short)(r >> 16);
}
static __device__ __forceinline__ float bf2f(unsigned short u) {
    union { unsigned u; float f; } v; v.u = ((unsigned)u) << 16;
    return v.f;
}

// ------------------------------------------------ weight convert (fp32->bf16)
__global__ __launch_bounds__(256) void wconv_kernel(
    const float* __restrict__ Wq, const float* __restrict__ Wk,
    const float* __restrict__ Wv, unsigned short* __restrict__ wq,
    unsigned short* __restrict__ wk, unsigned short* __restrict__ wv)
{
    const int i = blockIdx.x * 256 + threadIdx.x;   // 320 blocks -> 81920
    if (i < 8192)            wq[i] = f2bf(Wq[i] * LOG2E);
    else if (i < 16384)      wk[i - 8192] = f2bf(Wk[i - 8192]);
    else                     wv[i - 16384] = f2bf(Wv[i - 16384]);
}

// --------------------------------------------------- fused f,g,h producer
// R9 version: x LDS stage + 2-pass h (32 acc regs/pass), wave-private h stage.
#define XPITCH 264
#define HSPITCH 72
__global__ __launch_bounds__(256, 2) void producer_kernel(
    const float* __restrict__ x, const unsigned short* __restrict__ wq,
    const unsigned short* __restrict__ wk, const unsigned short* __restrict__ wv,
    unsigned short* __restrict__ f_t, unsigned short* __restrict__ g_t,
    unsigned short* __restrict__ h_bf, float* __restrict__ normg,
    float* __restrict__ pmax)
{
    __shared__ unsigned short xh_s[64 * XPITCH];        // 33.8 KB x-tile [n][c]
    __shared__ unsigned short hst[4 * 32 * HSPITCH];    // 18 KB h stage (wave-private)
    __shared__ unsigned short fg_s[4 * 2 * 512];        // 8 KB

    const int tid  = threadIdx.x;
    const int w    = tid >> 6;
    const int lane = tid & 63;
    const int q    = lane >> 4;
    const int r    = lane & 15;
    const int b    = blockIdx.x & 7;     // XCD pin
    const int nt   = blockIdx.x >> 3;
    const int n0   = nt << 6;
    const size_t bN = (size_t)b << 12;
    const f32x4 zero = {0.f, 0.f, 0.f, 0.f};

    // ---- stage x[b, :, n0..n0+64) as bf16, layout [n][c], pitch XPITCH ----
#pragma unroll
    for (int jj = 0; jj < 4; jj++) {
        const int task = jj * 256 + tid;
        const int n4 = task & 15;
        const int c4 = task >> 4;
        float va[4][4];
#pragma unroll
        for (int i = 0; i < 4; i++) {
            const f32x4 v = __builtin_nontemporal_load(
                (const f32x4*)(x + ((size_t)b << 20)
                               + (size_t)(c4 * 4 + i) * 4096 + n0) + n4);
            va[i][0] = v.x; va[i][1] = v.y; va[i][2] = v.z; va[i][3] = v.w;
        }
#pragma unroll
        for (int i = 0; i < 4; i++) {
            us4 t;
            t.x = f2bf(va[0][i]); t.y = f2bf(va[1][i]);
            t.z = f2bf(va[2][i]); t.w = f2bf(va[3][i]);
            *(us4*)(xh_s + (n4 * 4 + i) * XPITCH + c4 * 4) = t;
        }
    }
    __syncthreads();
    // xh_s is read-only from here on -> no further block barriers needed.

    f32x4 accf[2], accg[2];
    accf[0] = accf[1] = accg[0] = accg[1] = zero;

#pragma unroll
    for (int pass = 0; pass < 2; pass++) {
        f32x4 acch[2][4];
#pragma unroll
        for (int cs = 0; cs < 2; cs++)
#pragma unroll
            for (int ns = 0; ns < 4; ns++) acch[cs][ns] = zero;

        for (int ks = 0; ks < 8; ks++) {
            const int kof = ks * 32 + q * 8;
            const bf16x8 av0 = *(const bf16x8*)(wv + (size_t)(w * 64 + pass * 32 + r) * 256 + kof);
            const bf16x8 av1 = *(const bf16x8*)(wv + (size_t)(w * 64 + pass * 32 + 16 + r) * 256 + kof);
            bf16x8 aq0, aq1, ak0, ak1;
            if (pass == 0) {
                aq0 = *(const bf16x8*)(wq + (size_t)(r) * 256 + kof);
                aq1 = *(const bf16x8*)(wq + (size_t)(16 + r) * 256 + kof);
                ak0 = *(const bf16x8*)(wk + (size_t)(r) * 256 + kof);
                ak1 = *(const bf16x8*)(wk + (size_t)(16 + r) * 256 + kof);
            }
#pragma unroll
            for (int ns = 0; ns < 4; ns++) {
                const bf16x8 bx = *(const bf16x8*)(xh_s + (ns * 16 + r) * XPITCH + kof);
                acch[0][ns] = __builtin_amdgcn_mfma_f32_16x16x32_bf16(av0, bx, acch[0][ns], 0, 0, 0);
                acch[1][ns] = __builtin_amdgcn_mfma_f32_16x16x32_bf16(av1, bx, acch[1][ns], 0, 0, 0);
                if (pass == 0 && ns == w) {
                    accf[0] = __builtin_amdgcn_mfma_f32_16x16x32_bf16(aq0, bx, accf[0], 0, 0, 0);
                    accf[1] = __builtin_amdgcn_mfma_f32_16x16x32_bf16(aq1, bx, accf[1], 0, 0, 0);
                    accg[0] = __builtin_amdgcn_mfma_f32_16x16x32_bf16(ak0, bx, accg[0], 0, 0, 0);
                    accg[1] = __builtin_amdgcn_mfma_f32_16x16x32_bf16(ak1, bx, accg[1], 0, 0, 0);
                }
            }
        }

        // ---- f/g output + norms (pass 0 only; all wave-local) ----
        if (pass == 0) {
            unsigned short* lf = fg_s + w * 1024;
            unsigned short* lg = lf + 512;
#pragma unroll
            for (int ms = 0; ms < 2; ms++)
#pragma unroll
                for (int reg = 0; reg < 4; reg++) {
                    lf[r * 32 + ms * 16 + q * 4 + reg] = f2bf(fmaxf(accf[ms][reg], 0.f));
                    lg[r * 32 + ms * 16 + q * 4 + reg] = f2bf(fmaxf(accg[ms][reg], 0.f));
                }
            const bf16x8 ffrag = *(const bf16x8*)(lf + r * 32 + q * 8);
            const bf16x8 gfrag = *(const bf16x8*)(lg + r * 32 + q * 8);
            *(bf16x8*)(f_t + ((bN + n0 + w * 16 + r) << 5) + q * 8) = ffrag;
            *(bf16x8*)(g_t + ((bN + n0 + w * 16 + r) << 5) + q * 8) = gfrag;

            float nf2 = 0.f, ng2 = 0.f;
#pragma unroll
            for (int i = 0; i < 8; i++) {
                const float fv = bf2f(((unsigned short*)&ffrag)[i]);
                const float gv = bf2f(((unsigned short*)&gfrag)[i]);
                nf2 += fv * fv; ng2 += gv * gv;
            }
            nf2 += __shfl_xor(nf2, 16); nf2 += __shfl_xor(nf2, 32);
            ng2 += __shfl_xor(ng2, 16); ng2 += __shfl_xor(ng2, 32);
            if (q == 0) normg[bN + n0 + w * 16 + r] = sqrtf(ng2);
            float nf = sqrtf(nf2);
#pragma unroll
            for (int off = 1; off < 16; off <<= 1) nf = fmaxf(nf, __shfl_xor(nf, off));
            if (lane == 0) pmax[(b << 8) + nt * 4 + w] = nf;
        }

        // ---- stage h (relu) wave-privately, then store 32 rows of 128B ----
        unsigned short* hs = hst + w * (32 * HSPITCH);
#pragma unroll
        for (int cs = 0; cs < 2; cs++)
#pragma unroll
            for (int ns = 0; ns < 4; ns++)
#pragma unroll
                for (int reg = 0; reg < 4; reg++)
                    hs[(cs * 16 + q * 4 + reg) * HSPITCH + ns * 16 + r] =
                        f2bf(fmaxf(acch[cs][ns][reg], 0.f));
        const size_t hdst = (((size_t)(b * 64 + nt)) << 14)
                          + (size_t)(w * 64 + pass * 32) * 64;
#pragma unroll
        for (int p = 0; p < 4; p++) {
            const int cl = p * 8 + (lane >> 3);
            const int kk = lane & 7;
            *(bf16x8*)(h_bf + hdst + cl * 64 + kk * 8) =
                *(const bf16x8*)(hs + cl * HSPITCH + kk * 8);
        }
    }
}

// ------------------------------------------------------- MFMA attention
// EXACT R8: 512 thr / 8 waves. Wave w: c-range [w*32, +32), produces 16
// n-rows of the 128-n P tile. acc[2][4]=32 AGPR; 3-slot XOR-swizzled P,
// 1 barrier/iter; launch_bounds(512,4); no setprio.
__global__ __launch_bounds__(512, 4) void attn_kernel(
    const unsigned short* __restrict__ f_t, const unsigned short* __restrict__ g_t,
    const unsigned short* __restrict__ h_bf, const float* __restrict__ x,
    const float* __restrict__ gamma, const float* __restrict__ normg,
    const float* __restrict__ pmax, float* __restrict__ out)
{
    __shared__ unsigned short p_s[3][64 * 128];  // [slot][m][n], XOR-swizzled
    __shared__ float red_l[8][64];
    __shared__ float sLi[64];

    const int tid  = threadIdx.x;
    const int w    = tid >> 6;      // wave 0..7
    const int lane = tid & 63;
    const int q    = lane >> 4;
    const int r    = lane & 15;
    const int b    = blockIdx.x & 7;          // XCD pin
    const int m0   = (blockIdx.x >> 3) << 6;

    const size_t bN = (size_t)b << 12;
    const int c0 = w << 5;                    // 32 channels per wave

    // reduce per-wave f-norm partials (256 floats, L2-hit) -> mnf
    float pv = pmax[(b << 8) + lane];
    pv = fmaxf(pv, pmax[(b << 8) + 64 + lane]);
    pv = fmaxf(pv, pmax[(b << 8) + 128 + lane]);
    pv = fmaxf(pv, pmax[(b << 8) + 192 + lane]);
#pragma unroll
    for (int off = 1; off < 64; off <<= 1) pv = fmaxf(pv, __shfl_xor(pv, off));
    const float mnf = pv;

    bf16x8 bg[4];
    float nMh[4];
#pragma unroll
    for (int ms = 0; ms < 4; ms++) {
        bg[ms] = *(const bf16x8*)(g_t + ((bN + m0 + ms * 16 + r) << 5) + (q << 3));
        nMh[ms] = -(mnf * normg[bN + m0 + ms * 16 + r] * 1.0002f);
    }

    f32x4 acc[2][4];
    const f32x4 zero = {0.f, 0.f, 0.f, 0.f};
#pragma unroll
    for (int cs = 0; cs < 2; cs++)
#pragma unroll
        for (int ms = 0; ms < 4; ms++) acc[cs][ms] = zero;
    float lt[4] = {0.f, 0.f, 0.f, 0.f};

    // swizzle: 16B chunk idx within a 256B row, phys = (idx&8)|((idx^r)&7)
    const int wchunk = (w << 1) + (q >> 1);                         // write: 0..15
    const int wphys  = (wchunk & 8) | ((wchunk ^ r) & 7);
    const int woff   = (wphys << 3) + ((q & 1) << 2);               // u16 units

    auto ldf = [&](int t) {   // f rows n = t*128 + w*16 + r
        return *(const bf16x8*)(f_t + ((bN + (t << 7) + (w << 4) + r) << 5) + (q << 3));
    };
    auto produce = [&](const bf16x8 af, unsigned short* pb) {
#pragma unroll
        for (int ms = 0; ms < 4; ms++) {
            f32x4 ci; ci[0] = ci[1] = ci[2] = ci[3] = nMh[ms];
            const f32x4 sv = __builtin_amdgcn_mfma_f32_16x16x32_bf16(af, bg[ms], ci, 0, 0, 0);
            const float e0 = __builtin_amdgcn_exp2f(sv[0]);
            const float e1 = __builtin_amdgcn_exp2f(sv[1]);
            const float e2 = __builtin_amdgcn_exp2f(sv[2]);
            const float e3 = __builtin_amdgcn_exp2f(sv[3]);
            lt[ms] += (e0 + e1) + (e2 + e3);
            uint2 pk;
            pk.x = __builtin_amdgcn_perm(__float_as_uint(e1), __float_as_uint(e0), 0x07060302u);
            pk.y = __builtin_amdgcn_perm(__float_as_uint(e3), __float_as_uint(e2), 0x07060302u);
            *(uint2*)(pb + ((ms * 16 + r) << 7) + woff) = pk;
        }
    };

    bf16x8 afn = ldf(0);
    produce(afn, p_s[0]);
    afn = ldf(1);

    int sr = 0, sw = 1;
    for (int t = 0; t < 32; t++) {
        __syncthreads();
        // h A-fragments for PV(t): tiled layout [b][nt64][c][64]
        bf16x8 ah[2][4];
#pragma unroll
        for (int ch = 0; ch < 4; ch++) {
            const unsigned short* hb =
                h_bf + (((size_t)(b * 64 + t * 2 + (ch >> 1))) << 14) + ((ch & 1) << 5) + (q << 3);
#pragma unroll
            for (int cs = 0; cs < 2; cs++)
                ah[cs][ch] = *(const bf16x8*)(hb + ((c0 + cs * 16 + r) << 6));
        }
        if (t < 31) {
            const bf16x8 afc = afn;
            if (t < 30) afn = ldf(t + 2);
            produce(afc, p_s[sw]);
        }
        const unsigned short* pb = p_s[sr];
#pragma unroll
        for (int ch = 0; ch < 4; ch++) {
            bf16x8 bp[4];
#pragma unroll
            for (int ms = 0; ms < 4; ms++) {
                const int idx  = (ch << 2) + q;
                const int phys = (idx & 8) | ((idx ^ r) & 7);
                bp[ms] = *(const bf16x8*)(pb + ((ms * 16 + r) << 7) + (phys << 3));
            }
#pragma unroll
            for (int cs = 0; cs < 2; cs++)
#pragma unroll
                for (int ms = 0; ms < 4; ms++)
                    acc[cs][ms] = __builtin_amdgcn_mfma_f32_16x16x32_bf16(
                        ah[cs][ch], bp[ms], acc[cs][ms], 0, 0, 0);
        }
        sr = sw;
        sw = (sw == 2) ? 0 : sw + 1;
    }

    // ---------------- L reduction ------------------------------------------
#pragma unroll
    for (int ms = 0; ms < 4; ms++) {
        lt[ms] += __shfl_xor(lt[ms], 16);
        lt[ms] += __shfl_xor(lt[ms], 32);
    }
    __syncthreads();
    if (q == 0)
#pragma unroll
        for (int ms = 0; ms < 4; ms++) red_l[w][ms * 16 + r] = lt[ms];
    __syncthreads();
    if (tid < 64) {
        float L = 0.f;
#pragma unroll
        for (int ww = 0; ww < 8; ww++) L += red_l[ww][tid];
        sLi[tid] = 1.f / L;
    }
    __syncthreads();

    // ---------------- epilogue: (gamma/L) * O + x (nontemporal) ------------
    const float gm = gamma[0];
#pragma unroll
    for (int cs = 0; cs < 2; cs++) {
#pragma unroll
        for (int ms = 0; ms < 4; ms++) {
            const float gl = gm * sLi[ms * 16 + r];
#pragma unroll
            for (int reg = 0; reg < 4; reg++) {
                const int c = c0 + cs * 16 + q * 4 + reg;
                const size_t a = (((size_t)b * 256 + c) << 12) + m0 + ms * 16 + r;
                const float xv = __builtin_nontemporal_load(x + a);
                __builtin_nontemporal_store(gl * acc[cs][ms][reg] + xv, out + a);
            }
        }
    }
}

// ------------------------------------------------------------------- launch
extern "C" void kernel_launch(void* const* d_in, const int* in_sizes, int n_in,
                              void* d_out, int out_size, void* d_ws, size_t ws_size,
                              hipStream_t stream) {
    const float* x     = (const float*)d_in[0];
    const float* Wq    = (const float*)d_in[1];
    const float* Wk    = (const float*)d_in[2];
    const float* Wv    = (const float*)d_in[3];
    const float* gamma = (const float*)d_in[4];
    float* out = (float*)d_out;

    char* ws = (char*)d_ws;
    unsigned short* f_t  = (unsigned short*)ws;                        // 2 MB
    unsigned short* g_t  = (unsigned short*)(ws + (2u << 20));         // 2 MB
    unsigned short* h_bf = (unsigned short*)(ws + (4u << 20));         // 16 MB
    float*          ng   = (float*)(ws + (20u << 20));                 // 128 KB
    float*          pmx  = (float*)(ws + (20u << 20) + (1u << 17));    // 8 KB
    unsigned short* wq   = (unsigned short*)(ws + (21u << 20));        // 16 KB
    unsigned short* wk   = wq + 8192;                                  // 16 KB
    unsigned short* wv   = wk + 8192;                                  // 128 KB

    wconv_kernel<<<dim3(320), 256, 0, stream>>>(Wq, Wk, Wv, wq, wk, wv);
    producer_kernel<<<dim3(512), 256, 0, stream>>>(x, wq, wk, wv, f_t, g_t, h_bf, ng, pmx);
    attn_kernel<<<dim3(512), 512, 0, stream>>>(f_t, g_t, h_bf, x, gamma, ng, pmx, out);
}